// Round 1
// baseline (338.114 us; speedup 1.0000x reference)
//
#include <hip/hip_runtime.h>

#define DM 768
#define NH 12
#define DH 64
#define BB 8
#define SS 1024
#define BS (BB*SS)      /* 8192 */
#define QKVN (3*DM)     /* 2304 */

typedef __attribute__((ext_vector_type(8))) __bf16 bf16x8;
typedef __attribute__((ext_vector_type(4))) float  f32x4;

__device__ __forceinline__ unsigned short f2bf(float f){
  union { float f; unsigned u; } v; v.f = f;
  unsigned r = v.u + 0x7FFFu + ((v.u >> 16) & 1u);
  return (unsigned short)(r >> 16);
}

__device__ __forceinline__ f32x4 mfma_bf16(bf16x8 a, bf16x8 b, f32x4 c){
  return __builtin_amdgcn_mfma_f32_16x16x32_bf16(a, b, c, 0, 0, 0);
}

// async global->LDS, 16B per lane. LDS dest must be wave-uniform base + lane*16.
__device__ __forceinline__ void lds16(const unsigned short* g, unsigned short* l){
  __builtin_amdgcn_global_load_lds(
      (const __attribute__((address_space(1))) void*)g,
      (__attribute__((address_space(3))) void*)l, 16, 0, 0);
}

__device__ __forceinline__ float redmax16(float v){
  v = fmaxf(v, __shfl_xor(v, 1, 64));
  v = fmaxf(v, __shfl_xor(v, 2, 64));
  v = fmaxf(v, __shfl_xor(v, 4, 64));
  v = fmaxf(v, __shfl_xor(v, 8, 64));
  return v;
}
__device__ __forceinline__ float redsum16(float v){
  v += __shfl_xor(v, 1, 64);
  v += __shfl_xor(v, 2, 64);
  v += __shfl_xor(v, 4, 64);
  v += __shfl_xor(v, 8, 64);
  return v;
}

// ---------------- prep kernels ----------------

__global__ void k_cvt_bf16(const float* __restrict__ src, unsigned short* __restrict__ dst, int n4){
  int i = blockIdx.x*blockDim.x + threadIdx.x;
  int stride = gridDim.x*blockDim.x;
  for (; i < n4; i += stride){
    float4 f = reinterpret_cast<const float4*>(src)[i];
    ushort4 u;
    u.x = f2bf(f.x); u.y = f2bf(f.y); u.z = f2bf(f.z); u.w = f2bf(f.w);
    reinterpret_cast<ushort4*>(dst)[i] = u;
  }
}

// batched transpose: src fp32 [B][R][C] -> dst bf16 [B][C][R]; R,C multiples of 64
__global__ void k_transpose_bf16(const float* __restrict__ src, unsigned short* __restrict__ dst,
                                 int R, int C){
  __shared__ float t[64][65];
  int c0 = blockIdx.x*64, r0 = blockIdx.y*64, bb = blockIdx.z;
  src += (size_t)bb * R * C;
  dst += (size_t)bb * R * C;
  int tx = threadIdx.x & 63, ty = threadIdx.x >> 6;
  #pragma unroll
  for (int r = ty; r < 64; r += 4)
    t[r][tx] = src[(size_t)(r0 + r)*C + c0 + tx];
  __syncthreads();
  #pragma unroll
  for (int cc = ty; cc < 64; cc += 4)
    dst[(size_t)(c0 + cc)*R + r0 + tx] = f2bf(t[tx][cc]);
}

// ---------------- GEMM core (m97 structure: 128x128 tile, BK=64, 4 waves) ----------------
// C = A[M][K] * Bt[N][K]^T, bf16 in, fp32 acc. Linear LDS, global_load_lds width 16.

__device__ __forceinline__ void gemm_core(const unsigned short* __restrict__ A,
    const unsigned short* __restrict__ Bt, int Kd, int brow, int bcol,
    unsigned short* lA, unsigned short* lB, f32x4 acc[4][4], int lane, int wr, int wc){
  const int tid = threadIdx.x;
  #pragma unroll
  for (int m=0;m<4;m++)
    #pragma unroll
    for (int n=0;n<4;n++) acc[m][n] = (f32x4){0.f,0.f,0.f,0.f};
  for (int k0 = 0; k0 < Kd; k0 += 64){
    #pragma unroll
    for (int q=0;q<4;q++){
      int flat = q*256 + tid;          // 0..1023 : 128 rows x 8 chunks of 8 bf16
      int row = flat >> 3, ch = flat & 7;
      lds16(A  + (size_t)(brow+row)*Kd + k0 + ch*8, lA + (size_t)flat*8);
      lds16(Bt + (size_t)(bcol+row)*Kd + k0 + ch*8, lB + (size_t)flat*8);
    }
    __syncthreads();
    #pragma unroll
    for (int kk=0;kk<2;kk++){
      bf16x8 af[4], bfr[4];
      #pragma unroll
      for (int m=0;m<4;m++)
        af[m] = *reinterpret_cast<const bf16x8*>(lA + (wr*64 + m*16 + (lane&15))*64 + kk*32 + (lane>>4)*8);
      #pragma unroll
      for (int n=0;n<4;n++)
        bfr[n] = *reinterpret_cast<const bf16x8*>(lB + (wc*64 + n*16 + (lane&15))*64 + kk*32 + (lane>>4)*8);
      #pragma unroll
      for (int m=0;m<4;m++)
        #pragma unroll
        for (int n=0;n<4;n++)
          acc[m][n] = mfma_bf16(af[m], bfr[n], acc[m][n]);
    }
    __syncthreads();
  }
}

// QKV GEMM: X[8192][768] * Wqkv_t[2304][768]^T.  Epilogue: Q scaled 1/8, V stored transposed.
__global__ void k_gemm_qkv(const unsigned short* __restrict__ X, const unsigned short* __restrict__ Wt,
    const float* __restrict__ bQ, const float* __restrict__ bK, const float* __restrict__ bV,
    unsigned short* __restrict__ Qo, unsigned short* __restrict__ Ko, unsigned short* __restrict__ Vo){
  __shared__ __align__(16) unsigned short lA[128*64];
  __shared__ __align__(16) unsigned short lB[128*64];
  const int bcol = blockIdx.x*128, brow = blockIdx.y*128;
  const int tid = threadIdx.x, lane = tid & 63, wid = tid >> 6;
  const int wr = wid >> 1, wc = wid & 1;
  f32x4 acc[4][4];
  gemm_core(X, Wt, DM, brow, bcol, lA, lB, acc, lane, wr, wc);
  #pragma unroll
  for (int m=0;m<4;m++){
    int r = brow + wr*64 + m*16 + ((lane>>4)<<2);
    int b = r >> 10, s = r & 1023;
    #pragma unroll
    for (int n=0;n<4;n++){
      int c = bcol + wc*64 + n*16 + (lane&15);
      int sel = c / DM;
      int hd = c - sel*DM;
      int h = hd >> 6, d = hd & 63;
      if (sel == 0){
        float bias = bQ[hd];
        unsigned short* dst = Qo + ((size_t)(b*NH + h)*SS + s)*DH + d;
        #pragma unroll
        for (int j=0;j<4;j++) dst[(size_t)j*DH] = f2bf((acc[m][n][j] + bias) * 0.125f);
      } else if (sel == 1){
        float bias = bK[hd];
        unsigned short* dst = Ko + ((size_t)(b*NH + h)*SS + s)*DH + d;
        #pragma unroll
        for (int j=0;j<4;j++) dst[(size_t)j*DH] = f2bf(acc[m][n][j] + bias);
      } else {
        float bias = bV[hd];
        unsigned short* dst = Vo + ((size_t)(b*NH + h)*DH + d)*SS + s;  // V^T: [bh][d][s]
        #pragma unroll
        for (int j=0;j<4;j++) dst[j] = f2bf(acc[m][n][j] + bias);
      }
    }
  }
}

// Output GEMM: Z[8192][768] * Wo_t[768][768]^T + b_O -> fp32 out
__global__ void k_gemm_out(const unsigned short* __restrict__ Z, const unsigned short* __restrict__ Wot,
    const float* __restrict__ bO, float* __restrict__ Out){
  __shared__ __align__(16) unsigned short lA[128*64];
  __shared__ __align__(16) unsigned short lB[128*64];
  const int bcol = blockIdx.x*128, brow = blockIdx.y*128;
  const int tid = threadIdx.x, lane = tid & 63, wid = tid >> 6;
  const int wr = wid >> 1, wc = wid & 1;
  f32x4 acc[4][4];
  gemm_core(Z, Wot, DM, brow, bcol, lA, lB, acc, lane, wr, wc);
  #pragma unroll
  for (int m=0;m<4;m++){
    int r = brow + wr*64 + m*16 + ((lane>>4)<<2);
    #pragma unroll
    for (int n=0;n<4;n++){
      int c = bcol + wc*64 + n*16 + (lane&15);
      float bias = bO[c];
      float* dst = Out + (size_t)r*DM + c;
      #pragma unroll
      for (int j=0;j<4;j++) dst[(size_t)j*DM] = acc[m][n][j] + bias;
    }
  }
}

// ---------------- flash attention (causal) ----------------
// grid (8 q-blocks of 128, 96 bh). 4 waves x 32 q-rows. K/Vt staged in swizzled LDS.
__global__ void k_attn(const unsigned short* __restrict__ Qp, const unsigned short* __restrict__ Kp,
                       const unsigned short* __restrict__ Vp, unsigned short* __restrict__ Zp){
  __shared__ __align__(16) unsigned short kl[64*64];
  __shared__ __align__(16) unsigned short vl[64*64];
  __shared__ __align__(16) unsigned short pl[4*32*64];
  const int bh = blockIdx.y;
  const int q0 = blockIdx.x * 128;
  const int tid = threadIdx.x;
  const int lane = tid & 63;
  const int w = tid >> 6;
  const int lr = lane & 15;
  const int lg = lane >> 4;
  const unsigned short* Qb = Qp + (size_t)bh * (SS*DH);
  const unsigned short* Kb = Kp + (size_t)bh * (SS*DH);
  const unsigned short* Vb = Vp + (size_t)bh * (DH*SS);
  const int qmin = q0 + w*32;

  // Q fragments hoisted (pre-scaled by 1/8 at projection)
  bf16x8 aq[2][2];
  #pragma unroll
  for (int rb=0;rb<2;rb++)
    #pragma unroll
    for (int kk=0;kk<2;kk++)
      aq[rb][kk] = *reinterpret_cast<const bf16x8*>(Qb + (size_t)(qmin + rb*16 + lr)*DH + kk*32 + lg*8);

  f32x4 o[2][4];
  float mrow[2][4], lrow[2][4];
  #pragma unroll
  for (int rb=0;rb<2;rb++){
    #pragma unroll
    for (int db=0;db<4;db++) o[rb][db] = (f32x4){0.f,0.f,0.f,0.f};
    #pragma unroll
    for (int j=0;j<4;j++){ mrow[rb][j] = -1e30f; lrow[rb][j] = 0.f; }
  }

  const int nkv = (q0 >> 6) + 2;
  unsigned short* pw = pl + w*(32*64);

  for (int it = 0; it < nkv; ++it){
    const int kv0 = it * 64;
    // stage K (64x64) and Vt (64x64): linear LDS dest, XOR-pre-swizzled global source
    #pragma unroll
    for (int qq=0; qq<2; qq++){
      int flat = qq*256 + tid;          // 0..511 : 64 rows x 8 chunks
      int row = flat >> 3, ch = flat & 7;
      int sch = ch ^ (row & 7);
      lds16(Kb + (size_t)(kv0+row)*DH + sch*8, kl + (size_t)flat*8);
      lds16(Vb + (size_t)row*SS + kv0 + sch*8, vl + (size_t)flat*8);
    }
    __syncthreads();
    if (kv0 <= qmin + 31){              // wave has >=1 unmasked column in this kv block
      // S = Q K^T (pre-scaled)
      f32x4 sf[2][4];
      #pragma unroll
      for (int cb=0;cb<4;cb++){
        int krow = cb*16 + lr;
        bf16x8 bk0 = *reinterpret_cast<const bf16x8*>(kl + krow*64 + ((lg       ^ (krow&7))<<3));
        bf16x8 bk1 = *reinterpret_cast<const bf16x8*>(kl + krow*64 + (((4+lg)   ^ (krow&7))<<3));
        #pragma unroll
        for (int rb=0;rb<2;rb++){
          f32x4 t = (f32x4){0.f,0.f,0.f,0.f};
          t = mfma_bf16(aq[rb][0], bk0, t);
          t = mfma_bf16(aq[rb][1], bk1, t);
          sf[rb][cb] = t;
        }
      }
      // causal mask
      if (kv0 + 64 > qmin){
        #pragma unroll
        for (int rb=0;rb<2;rb++)
          #pragma unroll
          for (int cb=0;cb<4;cb++)
            #pragma unroll
            for (int j=0;j<4;j++){
              int qrow = qmin + rb*16 + lg*4 + j;
              int kv   = kv0 + cb*16 + lr;
              if (kv > qrow) sf[rb][cb][j] = -1e30f;
            }
      }
      // online softmax (wave-parallel reduce within 16-lane groups)
      #pragma unroll
      for (int rb=0;rb<2;rb++){
        #pragma unroll
        for (int j=0;j<4;j++){
          float pm = fmaxf(fmaxf(sf[rb][0][j], sf[rb][1][j]), fmaxf(sf[rb][2][j], sf[rb][3][j]));
          pm = redmax16(pm);
          float mn = fmaxf(mrow[rb][j], pm);
          float sc = __expf(mrow[rb][j] - mn);
          mrow[rb][j] = mn;
          float rsum = 0.f;
          #pragma unroll
          for (int cb=0;cb<4;cb++){
            float p = __expf(sf[rb][cb][j] - mn);
            sf[rb][cb][j] = p;
            rsum += p;
          }
          rsum = redsum16(rsum);
          lrow[rb][j] = lrow[rb][j]*sc + rsum;
          #pragma unroll
          for (int db=0;db<4;db++) o[rb][db][j] *= sc;
        }
        // write P (bf16) to per-wave swizzled LDS
        #pragma unroll
        for (int cb=0;cb<4;cb++){
          int pcol = cb*16 + lr;
          #pragma unroll
          for (int j=0;j<4;j++){
            int prow = rb*16 + lg*4 + j;
            pw[prow*64 + (((pcol>>3) ^ (prow&7))<<3) + (pcol&7)] = f2bf(sf[rb][cb][j]);
          }
        }
      }
      // PV: O += P * V   (A = P from LDS, B = Vt rows, contiguous-K)
      bf16x8 pa[2][2];
      #pragma unroll
      for (int rb=0;rb<2;rb++){
        int prow = rb*16 + lr;
        #pragma unroll
        for (int kk=0;kk<2;kk++)
          pa[rb][kk] = *reinterpret_cast<const bf16x8*>(pw + prow*64 + (((kk*4+lg) ^ (prow&7))<<3));
      }
      #pragma unroll
      for (int db=0;db<4;db++){
        int vrow = db*16 + lr;
        bf16x8 bv0 = *reinterpret_cast<const bf16x8*>(vl + vrow*64 + ((lg     ^ (vrow&7))<<3));
        bf16x8 bv1 = *reinterpret_cast<const bf16x8*>(vl + vrow*64 + (((4+lg) ^ (vrow&7))<<3));
        #pragma unroll
        for (int rb=0;rb<2;rb++){
          o[rb][db] = mfma_bf16(pa[rb][0], bv0, o[rb][db]);
          o[rb][db] = mfma_bf16(pa[rb][1], bv1, o[rb][db]);
        }
      }
    }
    __syncthreads();
  }
  // finalize: O/l -> Z [b][s][h*64+d] bf16
  const int b = bh / NH, h = bh - b*NH;
  #pragma unroll
  for (int rb=0;rb<2;rb++){
    float inv[4];
    #pragma unroll
    for (int j=0;j<4;j++) inv[j] = 1.f / lrow[rb][j];
    #pragma unroll
    for (int db=0;db<4;db++){
      #pragma unroll
      for (int j=0;j<4;j++){
        int s   = q0 + w*32 + rb*16 + lg*4 + j;
        int col = h*DH + db*16 + lr;
        Zp[(size_t)(b*SS + s)*DM + col] = f2bf(o[rb][db][j] * inv[j]);
      }
    }
  }
}

// ---------------- launch ----------------

extern "C" void kernel_launch(void* const* d_in, const int* in_sizes, int n_in,
                              void* d_out, int out_size, void* d_ws, size_t ws_size,
                              hipStream_t stream){
  const float* x  = (const float*)d_in[0];
  const float* wq = (const float*)d_in[1];
  const float* wk = (const float*)d_in[2];
  const float* wv = (const float*)d_in[3];
  const float* wo = (const float*)d_in[4];
  const float* bq = (const float*)d_in[5];
  const float* bk = (const float*)d_in[6];
  const float* bv = (const float*)d_in[7];
  const float* bo = (const float*)d_in[8];
  float* out = (float*)d_out;

  char* ws = (char*)d_ws;
  const size_t SZ_X  = (size_t)BS*DM*2;      // 12,582,912
  const size_t SZ_W  = (size_t)QKVN*DM*2;    //  3,538,944
  const size_t SZ_WO = (size_t)DM*DM*2;      //  1,179,648
  unsigned short* xbf   = (unsigned short*)(ws);
  unsigned short* wqkvt = (unsigned short*)(ws + SZ_X);
  unsigned short* wot   = (unsigned short*)(ws + SZ_X + SZ_W);
  unsigned short* Qw    = (unsigned short*)(ws + SZ_X + SZ_W + SZ_WO);
  unsigned short* Kw    = (unsigned short*)(ws + SZ_X + SZ_W + SZ_WO + SZ_X);
  unsigned short* Vw    = (unsigned short*)(ws + SZ_X + SZ_W + SZ_WO + 2*SZ_X);
  unsigned short* Zw    = xbf;               // x consumed by QKV GEMM before attn writes Z

  k_cvt_bf16<<<dim3(1024), dim3(256), 0, stream>>>(x, xbf, (BS*DM)/4);
  // W_Q/K/V: [12][768][64] -> [12][64][768]  (B^T layout rows c = qkv*768 + h*64 + d)
  k_transpose_bf16<<<dim3(1,12,12),  dim3(256), 0, stream>>>(wq, wqkvt,              DM, DH);
  k_transpose_bf16<<<dim3(1,12,12),  dim3(256), 0, stream>>>(wk, wqkvt +   DM*DM,    DM, DH);
  k_transpose_bf16<<<dim3(1,12,12),  dim3(256), 0, stream>>>(wv, wqkvt + 2*DM*DM,    DM, DH);
  // W_O: [768 hd][768 m] -> [768 m][768 hd]
  k_transpose_bf16<<<dim3(12,12,1),  dim3(256), 0, stream>>>(wo, wot, DM, DM);

  k_gemm_qkv<<<dim3(QKVN/128, BS/128), dim3(256), 0, stream>>>(xbf, wqkvt, bq, bk, bv, Qw, Kw, Vw);
  k_attn    <<<dim3(SS/128, BB*NH),    dim3(256), 0, stream>>>(Qw, Kw, Vw, Zw);
  k_gemm_out<<<dim3(DM/128, BS/128),   dim3(256), 0, stream>>>(Zw, wot, bo, out);
}

// Round 2
// 196.837 us; speedup vs baseline: 1.7177x; 1.7177x over previous
//
#include <hip/hip_runtime.h>

#define DM 768
#define NH 12
#define DH 64
#define BB 8
#define SS 1024
#define BS (BB*SS)      /* 8192 */
#define QKVN (3*DM)     /* 2304 */

typedef __attribute__((ext_vector_type(8))) __bf16 bf16x8;
typedef __attribute__((ext_vector_type(4))) float  f32x4;

__device__ __forceinline__ unsigned short f2bf(float f){
  union { float f; unsigned u; } v; v.f = f;
  unsigned r = v.u + 0x7FFFu + ((v.u >> 16) & 1u);
  return (unsigned short)(r >> 16);
}

__device__ __forceinline__ f32x4 mfma_bf16(bf16x8 a, bf16x8 b, f32x4 c){
  return __builtin_amdgcn_mfma_f32_16x16x32_bf16(a, b, c, 0, 0, 0);
}

// async global->LDS, 16B per lane. LDS dest must be wave-uniform base + lane*16.
__device__ __forceinline__ void lds16(const unsigned short* g, unsigned short* l){
  __builtin_amdgcn_global_load_lds(
      (const __attribute__((address_space(1))) void*)g,
      (__attribute__((address_space(3))) void*)l, 16, 0, 0);
}

__device__ __forceinline__ float redmax16(float v){
  v = fmaxf(v, __shfl_xor(v, 1, 64));
  v = fmaxf(v, __shfl_xor(v, 2, 64));
  v = fmaxf(v, __shfl_xor(v, 4, 64));
  v = fmaxf(v, __shfl_xor(v, 8, 64));
  return v;
}
__device__ __forceinline__ float redsum16(float v){
  v += __shfl_xor(v, 1, 64);
  v += __shfl_xor(v, 2, 64);
  v += __shfl_xor(v, 4, 64);
  v += __shfl_xor(v, 8, 64);
  return v;
}

// ---------------- prep kernels ----------------

__global__ __launch_bounds__(256, 4)
void k_cvt_bf16(const float* __restrict__ src, unsigned short* __restrict__ dst, int n4){
  int i = blockIdx.x*blockDim.x + threadIdx.x;
  int stride = gridDim.x*blockDim.x;
  for (; i < n4; i += stride){
    float4 f = reinterpret_cast<const float4*>(src)[i];
    ushort4 u;
    u.x = f2bf(f.x); u.y = f2bf(f.y); u.z = f2bf(f.z); u.w = f2bf(f.w);
    reinterpret_cast<ushort4*>(dst)[i] = u;
  }
}

// batched transpose: src fp32 [B][R][C] -> dst bf16 [B][C][R]; R,C multiples of 64
__global__ __launch_bounds__(256, 4)
void k_transpose_bf16(const float* __restrict__ src, unsigned short* __restrict__ dst,
                      int R, int C){
  __shared__ float t[64][65];
  int c0 = blockIdx.x*64, r0 = blockIdx.y*64, bb = blockIdx.z;
  src += (size_t)bb * R * C;
  dst += (size_t)bb * R * C;
  int tx = threadIdx.x & 63, ty = threadIdx.x >> 6;
  #pragma unroll
  for (int r = ty; r < 64; r += 4)
    t[r][tx] = src[(size_t)(r0 + r)*C + c0 + tx];
  __syncthreads();
  #pragma unroll
  for (int cc = ty; cc < 64; cc += 4)
    dst[(size_t)(c0 + cc)*R + r0 + tx] = f2bf(t[tx][cc]);
}

// ---------------- GEMM core (m97 structure: 128x128 tile, BK=64, 4 waves) ----------------
// C = A[M][K] * Bt[N][K]^T, bf16 in, fp32 acc. Linear LDS, global_load_lds width 16.

__device__ __forceinline__ void gemm_core(const unsigned short* __restrict__ A,
    const unsigned short* __restrict__ Bt, int Kd, int brow, int bcol,
    unsigned short* lA, unsigned short* lB, f32x4 acc[4][4], int lane, int wr, int wc){
  const int tid = threadIdx.x;
  #pragma unroll
  for (int m=0;m<4;m++)
    #pragma unroll
    for (int n=0;n<4;n++) acc[m][n] = (f32x4){0.f,0.f,0.f,0.f};
  for (int k0 = 0; k0 < Kd; k0 += 64){
    #pragma unroll
    for (int q=0;q<4;q++){
      int flat = q*256 + tid;          // 0..1023 : 128 rows x 8 chunks of 8 bf16
      int row = flat >> 3, ch = flat & 7;
      lds16(A  + (size_t)(brow+row)*Kd + k0 + ch*8, lA + (size_t)flat*8);
      lds16(Bt + (size_t)(bcol+row)*Kd + k0 + ch*8, lB + (size_t)flat*8);
    }
    __syncthreads();
    #pragma unroll
    for (int kk=0;kk<2;kk++){
      bf16x8 af[4], bfr[4];
      #pragma unroll
      for (int m=0;m<4;m++)
        af[m] = *reinterpret_cast<const bf16x8*>(lA + (wr*64 + m*16 + (lane&15))*64 + kk*32 + (lane>>4)*8);
      #pragma unroll
      for (int n=0;n<4;n++)
        bfr[n] = *reinterpret_cast<const bf16x8*>(lB + (wc*64 + n*16 + (lane&15))*64 + kk*32 + (lane>>4)*8);
      #pragma unroll
      for (int m=0;m<4;m++)
        #pragma unroll
        for (int n=0;n<4;n++)
          acc[m][n] = mfma_bf16(af[m], bfr[n], acc[m][n]);
    }
    __syncthreads();
  }
}

// QKV GEMM: X[8192][768] * Wqkv_t[2304][768]^T.  Epilogue: Q scaled 1/8, V stored transposed.
__global__ __launch_bounds__(256, 2)
void k_gemm_qkv(const unsigned short* __restrict__ X, const unsigned short* __restrict__ Wt,
    const float* __restrict__ bQ, const float* __restrict__ bK, const float* __restrict__ bV,
    unsigned short* __restrict__ Qo, unsigned short* __restrict__ Ko, unsigned short* __restrict__ Vo){
  __shared__ __align__(16) unsigned short lA[128*64];
  __shared__ __align__(16) unsigned short lB[128*64];
  const int bcol = blockIdx.x*128, brow = blockIdx.y*128;
  const int tid = threadIdx.x, lane = tid & 63, wid = tid >> 6;
  const int wr = wid >> 1, wc = wid & 1;
  f32x4 acc[4][4];
  gemm_core(X, Wt, DM, brow, bcol, lA, lB, acc, lane, wr, wc);
  #pragma unroll
  for (int m=0;m<4;m++){
    int r = brow + wr*64 + m*16 + ((lane>>4)<<2);
    int b = r >> 10, s = r & 1023;
    #pragma unroll
    for (int n=0;n<4;n++){
      int c = bcol + wc*64 + n*16 + (lane&15);
      int sel = c / DM;
      int hd = c - sel*DM;
      int h = hd >> 6, d = hd & 63;
      if (sel == 0){
        float bias = bQ[hd];
        unsigned short* dst = Qo + ((size_t)(b*NH + h)*SS + s)*DH + d;
        #pragma unroll
        for (int j=0;j<4;j++) dst[(size_t)j*DH] = f2bf((acc[m][n][j] + bias) * 0.125f);
      } else if (sel == 1){
        float bias = bK[hd];
        unsigned short* dst = Ko + ((size_t)(b*NH + h)*SS + s)*DH + d;
        #pragma unroll
        for (int j=0;j<4;j++) dst[(size_t)j*DH] = f2bf(acc[m][n][j] + bias);
      } else {
        float bias = bV[hd];
        unsigned short* dst = Vo + ((size_t)(b*NH + h)*DH + d)*SS + s;  // V^T: [bh][d][s]
        #pragma unroll
        for (int j=0;j<4;j++) dst[j] = f2bf(acc[m][n][j] + bias);
      }
    }
  }
}

// Output GEMM: Z[8192][768] * Wo_t[768][768]^T + b_O -> fp32 out
__global__ __launch_bounds__(256, 2)
void k_gemm_out(const unsigned short* __restrict__ Z, const unsigned short* __restrict__ Wot,
    const float* __restrict__ bO, float* __restrict__ Out){
  __shared__ __align__(16) unsigned short lA[128*64];
  __shared__ __align__(16) unsigned short lB[128*64];
  const int bcol = blockIdx.x*128, brow = blockIdx.y*128;
  const int tid = threadIdx.x, lane = tid & 63, wid = tid >> 6;
  const int wr = wid >> 1, wc = wid & 1;
  f32x4 acc[4][4];
  gemm_core(Z, Wot, DM, brow, bcol, lA, lB, acc, lane, wr, wc);
  #pragma unroll
  for (int m=0;m<4;m++){
    int r = brow + wr*64 + m*16 + ((lane>>4)<<2);
    #pragma unroll
    for (int n=0;n<4;n++){
      int c = bcol + wc*64 + n*16 + (lane&15);
      float bias = bO[c];
      float* dst = Out + (size_t)r*DM + c;
      #pragma unroll
      for (int j=0;j<4;j++) dst[(size_t)j*DM] = acc[m][n][j] + bias;
    }
  }
}

// ---------------- flash attention (causal) ----------------
// grid (8 q-blocks of 128, 96 bh). 4 waves x 32 q-rows. K/Vt staged in swizzled LDS.
__global__ __launch_bounds__(256, 2)
void k_attn(const unsigned short* __restrict__ Qp, const unsigned short* __restrict__ Kp,
            const unsigned short* __restrict__ Vp, unsigned short* __restrict__ Zp){
  __shared__ __align__(16) unsigned short kl[64*64];
  __shared__ __align__(16) unsigned short vl[64*64];
  __shared__ __align__(16) unsigned short pl[4*32*64];
  const int bh = blockIdx.y;
  const int q0 = blockIdx.x * 128;
  const int tid = threadIdx.x;
  const int lane = tid & 63;
  const int w = tid >> 6;
  const int lr = lane & 15;
  const int lg = lane >> 4;
  const unsigned short* Qb = Qp + (size_t)bh * (SS*DH);
  const unsigned short* Kb = Kp + (size_t)bh * (SS*DH);
  const unsigned short* Vb = Vp + (size_t)bh * (DH*SS);
  const int qmin = q0 + w*32;

  // Q fragments hoisted (pre-scaled by 1/8 at projection)
  bf16x8 aq[2][2];
  #pragma unroll
  for (int rb=0;rb<2;rb++)
    #pragma unroll
    for (int kk=0;kk<2;kk++)
      aq[rb][kk] = *reinterpret_cast<const bf16x8*>(Qb + (size_t)(qmin + rb*16 + lr)*DH + kk*32 + lg*8);

  f32x4 o[2][4];
  float mrow[2][4], lrow[2][4];
  #pragma unroll
  for (int rb=0;rb<2;rb++){
    #pragma unroll
    for (int db=0;db<4;db++) o[rb][db] = (f32x4){0.f,0.f,0.f,0.f};
    #pragma unroll
    for (int j=0;j<4;j++){ mrow[rb][j] = -1e30f; lrow[rb][j] = 0.f; }
  }

  const int nkv = (q0 >> 6) + 2;
  unsigned short* pw = pl + w*(32*64);

  for (int it = 0; it < nkv; ++it){
    const int kv0 = it * 64;
    // stage K (64x64) and Vt (64x64): linear LDS dest, XOR-pre-swizzled global source
    #pragma unroll
    for (int qq=0; qq<2; qq++){
      int flat = qq*256 + tid;          // 0..511 : 64 rows x 8 chunks
      int row = flat >> 3, ch = flat & 7;
      int sch = ch ^ (row & 7);
      lds16(Kb + (size_t)(kv0+row)*DH + sch*8, kl + (size_t)flat*8);
      lds16(Vb + (size_t)row*SS + kv0 + sch*8, vl + (size_t)flat*8);
    }
    __syncthreads();
    if (kv0 <= qmin + 31){              // wave has >=1 unmasked column in this kv block
      // S = Q K^T (pre-scaled)
      f32x4 sf[2][4];
      #pragma unroll
      for (int cb=0;cb<4;cb++){
        int krow = cb*16 + lr;
        bf16x8 bk0 = *reinterpret_cast<const bf16x8*>(kl + krow*64 + ((lg       ^ (krow&7))<<3));
        bf16x8 bk1 = *reinterpret_cast<const bf16x8*>(kl + krow*64 + (((4+lg)   ^ (krow&7))<<3));
        #pragma unroll
        for (int rb=0;rb<2;rb++){
          f32x4 t = (f32x4){0.f,0.f,0.f,0.f};
          t = mfma_bf16(aq[rb][0], bk0, t);
          t = mfma_bf16(aq[rb][1], bk1, t);
          sf[rb][cb] = t;
        }
      }
      // causal mask
      if (kv0 + 64 > qmin){
        #pragma unroll
        for (int rb=0;rb<2;rb++)
          #pragma unroll
          for (int cb=0;cb<4;cb++)
            #pragma unroll
            for (int j=0;j<4;j++){
              int qrow = qmin + rb*16 + lg*4 + j;
              int kv   = kv0 + cb*16 + lr;
              if (kv > qrow) sf[rb][cb][j] = -1e30f;
            }
      }
      // online softmax (wave-parallel reduce within 16-lane groups)
      #pragma unroll
      for (int rb=0;rb<2;rb++){
        #pragma unroll
        for (int j=0;j<4;j++){
          float pm = fmaxf(fmaxf(sf[rb][0][j], sf[rb][1][j]), fmaxf(sf[rb][2][j], sf[rb][3][j]));
          pm = redmax16(pm);
          float mn = fmaxf(mrow[rb][j], pm);
          float sc = __expf(mrow[rb][j] - mn);
          mrow[rb][j] = mn;
          float rsum = 0.f;
          #pragma unroll
          for (int cb=0;cb<4;cb++){
            float p = __expf(sf[rb][cb][j] - mn);
            sf[rb][cb][j] = p;
            rsum += p;
          }
          rsum = redsum16(rsum);
          lrow[rb][j] = lrow[rb][j]*sc + rsum;
          #pragma unroll
          for (int db=0;db<4;db++) o[rb][db][j] *= sc;
        }
        // write P (bf16) to per-wave swizzled LDS
        #pragma unroll
        for (int cb=0;cb<4;cb++){
          int pcol = cb*16 + lr;
          #pragma unroll
          for (int j=0;j<4;j++){
            int prow = rb*16 + lg*4 + j;
            pw[prow*64 + (((pcol>>3) ^ (prow&7))<<3) + (pcol&7)] = f2bf(sf[rb][cb][j]);
          }
        }
      }
      // PV: O += P * V   (A = P from LDS, B = Vt rows, contiguous-K)
      bf16x8 pa[2][2];
      #pragma unroll
      for (int rb=0;rb<2;rb++){
        int prow = rb*16 + lr;
        #pragma unroll
        for (int kk=0;kk<2;kk++)
          pa[rb][kk] = *reinterpret_cast<const bf16x8*>(pw + prow*64 + (((kk*4+lg) ^ (prow&7))<<3));
      }
      #pragma unroll
      for (int db=0;db<4;db++){
        int vrow = db*16 + lr;
        bf16x8 bv0 = *reinterpret_cast<const bf16x8*>(vl + vrow*64 + ((lg     ^ (vrow&7))<<3));
        bf16x8 bv1 = *reinterpret_cast<const bf16x8*>(vl + vrow*64 + (((4+lg) ^ (vrow&7))<<3));
        #pragma unroll
        for (int rb=0;rb<2;rb++){
          o[rb][db] = mfma_bf16(pa[rb][0], bv0, o[rb][db]);
          o[rb][db] = mfma_bf16(pa[rb][1], bv1, o[rb][db]);
        }
      }
    }
    __syncthreads();
  }
  // finalize: O/l -> Z [b][s][h*64+d] bf16
  const int b = bh / NH, h = bh - b*NH;
  #pragma unroll
  for (int rb=0;rb<2;rb++){
    float inv[4];
    #pragma unroll
    for (int j=0;j<4;j++) inv[j] = 1.f / lrow[rb][j];
    #pragma unroll
    for (int db=0;db<4;db++){
      #pragma unroll
      for (int j=0;j<4;j++){
        int s   = q0 + w*32 + rb*16 + lg*4 + j;
        int col = h*DH + db*16 + lr;
        Zp[(size_t)(b*SS + s)*DM + col] = f2bf(o[rb][db][j] * inv[j]);
      }
    }
  }
}

// ---------------- launch ----------------

extern "C" void kernel_launch(void* const* d_in, const int* in_sizes, int n_in,
                              void* d_out, int out_size, void* d_ws, size_t ws_size,
                              hipStream_t stream){
  const float* x  = (const float*)d_in[0];
  const float* wq = (const float*)d_in[1];
  const float* wk = (const float*)d_in[2];
  const float* wv = (const float*)d_in[3];
  const float* wo = (const float*)d_in[4];
  const float* bq = (const float*)d_in[5];
  const float* bk = (const float*)d_in[6];
  const float* bv = (const float*)d_in[7];
  const float* bo = (const float*)d_in[8];
  float* out = (float*)d_out;

  char* ws = (char*)d_ws;
  const size_t SZ_X  = (size_t)BS*DM*2;      // 12,582,912
  const size_t SZ_W  = (size_t)QKVN*DM*2;    //  3,538,944
  const size_t SZ_WO = (size_t)DM*DM*2;      //  1,179,648
  unsigned short* xbf   = (unsigned short*)(ws);
  unsigned short* wqkvt = (unsigned short*)(ws + SZ_X);
  unsigned short* wot   = (unsigned short*)(ws + SZ_X + SZ_W);
  unsigned short* Qw    = (unsigned short*)(ws + SZ_X + SZ_W + SZ_WO);
  unsigned short* Kw    = (unsigned short*)(ws + SZ_X + SZ_W + SZ_WO + SZ_X);
  unsigned short* Vw    = (unsigned short*)(ws + SZ_X + SZ_W + SZ_WO + 2*SZ_X);
  unsigned short* Zw    = xbf;               // x consumed by QKV GEMM before attn writes Z

  k_cvt_bf16<<<dim3(1024), dim3(256), 0, stream>>>(x, xbf, (BS*DM)/4);
  // W_Q/K/V: [12][768][64] -> [12][64][768]  (B^T layout rows c = qkv*768 + h*64 + d)
  k_transpose_bf16<<<dim3(1,12,12),  dim3(256), 0, stream>>>(wq, wqkvt,              DM, DH);
  k_transpose_bf16<<<dim3(1,12,12),  dim3(256), 0, stream>>>(wk, wqkvt +   DM*DM,    DM, DH);
  k_transpose_bf16<<<dim3(1,12,12),  dim3(256), 0, stream>>>(wv, wqkvt + 2*DM*DM,    DM, DH);
  // W_O: [768 hd][768 m] -> [768 m][768 hd]
  k_transpose_bf16<<<dim3(12,12,1),  dim3(256), 0, stream>>>(wo, wot, DM, DM);

  k_gemm_qkv<<<dim3(QKVN/128, BS/128), dim3(256), 0, stream>>>(xbf, wqkvt, bq, bk, bv, Qw, Kw, Vw);
  k_attn    <<<dim3(SS/128, BB*NH),    dim3(256), 0, stream>>>(Qw, Kw, Vw, Zw);
  k_gemm_out<<<dim3(DM/128, BS/128),   dim3(256), 0, stream>>>(Zw, wot, bo, out);
}

// Round 3
// 163.827 us; speedup vs baseline: 2.0639x; 1.2015x over previous
//
#include <hip/hip_runtime.h>

#define DM 768
#define NH 12
#define DH 64
#define BB 8
#define SS 1024
#define BS (BB*SS)      /* 8192 */
#define QKVN (3*DM)     /* 2304 */

typedef __attribute__((ext_vector_type(8))) __bf16 bf16x8;
typedef __attribute__((ext_vector_type(4))) float  f32x4;

__device__ __forceinline__ unsigned short f2bf(float f){
  union { float f; unsigned u; } v; v.f = f;
  unsigned r = v.u + 0x7FFFu + ((v.u >> 16) & 1u);
  return (unsigned short)(r >> 16);
}

__device__ __forceinline__ f32x4 mfma_bf16(bf16x8 a, bf16x8 b, f32x4 c){
  return __builtin_amdgcn_mfma_f32_16x16x32_bf16(a, b, c, 0, 0, 0);
}

// async global->LDS, 16B per lane. LDS dest must be wave-uniform base + lane*16.
__device__ __forceinline__ void lds16(const unsigned short* g, unsigned short* l){
  __builtin_amdgcn_global_load_lds(
      (const __attribute__((address_space(1))) void*)g,
      (__attribute__((address_space(3))) void*)l, 16, 0, 0);
}

__device__ __forceinline__ float redmax16(float v){
  v = fmaxf(v, __shfl_xor(v, 1, 64));
  v = fmaxf(v, __shfl_xor(v, 2, 64));
  v = fmaxf(v, __shfl_xor(v, 4, 64));
  v = fmaxf(v, __shfl_xor(v, 8, 64));
  return v;
}
__device__ __forceinline__ float redsum16(float v){
  v += __shfl_xor(v, 1, 64);
  v += __shfl_xor(v, 2, 64);
  v += __shfl_xor(v, 4, 64);
  v += __shfl_xor(v, 8, 64);
  return v;
}

// ---------------- prep kernels ----------------

__global__ __launch_bounds__(256, 4)
void k_cvt_bf16(const float* __restrict__ src, unsigned short* __restrict__ dst, int n4){
  int i = blockIdx.x*blockDim.x + threadIdx.x;
  int stride = gridDim.x*blockDim.x;
  for (; i < n4; i += stride){
    float4 f = reinterpret_cast<const float4*>(src)[i];
    ushort4 u;
    u.x = f2bf(f.x); u.y = f2bf(f.y); u.z = f2bf(f.z); u.w = f2bf(f.w);
    reinterpret_cast<ushort4*>(dst)[i] = u;
  }
}

// batched transpose: src fp32 [B][R][C] -> dst bf16 [B][C][R]; R,C multiples of 64
__global__ __launch_bounds__(256, 4)
void k_transpose_bf16(const float* __restrict__ src, unsigned short* __restrict__ dst,
                      int R, int C){
  __shared__ float t[64][65];
  int c0 = blockIdx.x*64, r0 = blockIdx.y*64, bb = blockIdx.z;
  src += (size_t)bb * R * C;
  dst += (size_t)bb * R * C;
  int tx = threadIdx.x & 63, ty = threadIdx.x >> 6;
  #pragma unroll
  for (int r = ty; r < 64; r += 4)
    t[r][tx] = src[(size_t)(r0 + r)*C + c0 + tx];
  __syncthreads();
  #pragma unroll
  for (int cc = ty; cc < 64; cc += 4)
    dst[(size_t)(c0 + cc)*R + r0 + tx] = f2bf(t[tx][cc]);
}

// ---------------- GEMM core (m97 structure: 128x128 tile, BK=64, 4 waves) ----------------
// C = A[M][K] * Bt[N][K]^T, bf16 in, fp32 acc. Linear LDS, global_load_lds width 16.

__device__ __forceinline__ void gemm_core(const unsigned short* __restrict__ A,
    const unsigned short* __restrict__ Bt, int Kd, int brow, int bcol,
    unsigned short* lA, unsigned short* lB, f32x4 acc[4][4], int lane, int wr, int wc){
  const int tid = threadIdx.x;
  #pragma unroll
  for (int m=0;m<4;m++)
    #pragma unroll
    for (int n=0;n<4;n++) acc[m][n] = (f32x4){0.f,0.f,0.f,0.f};
  for (int k0 = 0; k0 < Kd; k0 += 64){
    #pragma unroll
    for (int q=0;q<4;q++){
      int flat = q*256 + tid;          // 0..1023 : 128 rows x 8 chunks of 8 bf16
      int row = flat >> 3, ch = flat & 7;
      lds16(A  + (size_t)(brow+row)*Kd + k0 + ch*8, lA + (size_t)flat*8);
      lds16(Bt + (size_t)(bcol+row)*Kd + k0 + ch*8, lB + (size_t)flat*8);
    }
    __syncthreads();
    #pragma unroll
    for (int kk=0;kk<2;kk++){
      bf16x8 af[4], bfr[4];
      #pragma unroll
      for (int m=0;m<4;m++)
        af[m] = *reinterpret_cast<const bf16x8*>(lA + (wr*64 + m*16 + (lane&15))*64 + kk*32 + (lane>>4)*8);
      #pragma unroll
      for (int n=0;n<4;n++)
        bfr[n] = *reinterpret_cast<const bf16x8*>(lB + (wc*64 + n*16 + (lane&15))*64 + kk*32 + (lane>>4)*8);
      #pragma unroll
      for (int m=0;m<4;m++)
        #pragma unroll
        for (int n=0;n<4;n++)
          acc[m][n] = mfma_bf16(af[m], bfr[n], acc[m][n]);
    }
    __syncthreads();
  }
}

// QKV GEMM: X[8192][768] * Wqkv_t[2304][768]^T.  Epilogue: Q scaled 1/8, V stored transposed.
__global__ __launch_bounds__(256, 2)
void k_gemm_qkv(const unsigned short* __restrict__ X, const unsigned short* __restrict__ Wt,
    const float* __restrict__ bQ, const float* __restrict__ bK, const float* __restrict__ bV,
    unsigned short* __restrict__ Qo, unsigned short* __restrict__ Ko, unsigned short* __restrict__ Vo){
  __shared__ __align__(16) unsigned short lA[128*64];
  __shared__ __align__(16) unsigned short lB[128*64];
  const int bcol = blockIdx.x*128, brow = blockIdx.y*128;
  const int tid = threadIdx.x, lane = tid & 63, wid = tid >> 6;
  const int wr = wid >> 1, wc = wid & 1;
  f32x4 acc[4][4];
  gemm_core(X, Wt, DM, brow, bcol, lA, lB, acc, lane, wr, wc);
  #pragma unroll
  for (int m=0;m<4;m++){
    int r = brow + wr*64 + m*16 + ((lane>>4)<<2);
    int b = r >> 10, s = r & 1023;
    #pragma unroll
    for (int n=0;n<4;n++){
      int c = bcol + wc*64 + n*16 + (lane&15);
      int sel = c / DM;
      int hd = c - sel*DM;
      int h = hd >> 6, d = hd & 63;
      if (sel == 0){
        float bias = bQ[hd];
        unsigned short* dst = Qo + ((size_t)(b*NH + h)*SS + s)*DH + d;
        #pragma unroll
        for (int j=0;j<4;j++) dst[(size_t)j*DH] = f2bf((acc[m][n][j] + bias) * 0.125f);
      } else if (sel == 1){
        float bias = bK[hd];
        unsigned short* dst = Ko + ((size_t)(b*NH + h)*SS + s)*DH + d;
        #pragma unroll
        for (int j=0;j<4;j++) dst[(size_t)j*DH] = f2bf(acc[m][n][j] + bias);
      } else {
        float bias = bV[hd];
        unsigned short* dst = Vo + ((size_t)(b*NH + h)*DH + d)*SS + s;  // V^T: [bh][d][s]
        #pragma unroll
        for (int j=0;j<4;j++) dst[j] = f2bf(acc[m][n][j] + bias);
      }
    }
  }
}

// Output GEMM: Z[8192][768] * Wo_t[768][768]^T + b_O -> fp32 out
__global__ __launch_bounds__(256, 2)
void k_gemm_out(const unsigned short* __restrict__ Z, const unsigned short* __restrict__ Wot,
    const float* __restrict__ bO, float* __restrict__ Out){
  __shared__ __align__(16) unsigned short lA[128*64];
  __shared__ __align__(16) unsigned short lB[128*64];
  const int bcol = blockIdx.x*128, brow = blockIdx.y*128;
  const int tid = threadIdx.x, lane = tid & 63, wid = tid >> 6;
  const int wr = wid >> 1, wc = wid & 1;
  f32x4 acc[4][4];
  gemm_core(Z, Wot, DM, brow, bcol, lA, lB, acc, lane, wr, wc);
  #pragma unroll
  for (int m=0;m<4;m++){
    int r = brow + wr*64 + m*16 + ((lane>>4)<<2);
    #pragma unroll
    for (int n=0;n<4;n++){
      int c = bcol + wc*64 + n*16 + (lane&15);
      float bias = bO[c];
      float* dst = Out + (size_t)r*DM + c;
      #pragma unroll
      for (int j=0;j<4;j++) dst[(size_t)j*DM] = acc[m][n][j] + bias;
    }
  }
}

// ---------------- flash attention (causal, load-balanced, double-buffered) ----------------
// grid (8 pairs, 96 bh), 128 threads = 2 waves x 32 q-rows.
// Block (i, bh) processes 64-row q-tile i (i+1 kv tiles) then q-tile 15-i (16-i kv tiles):
// every block runs exactly 17 kv-iterations. K/V staged via 2-phase double buffer.

__device__ __forceinline__ void attn_stage(const unsigned short* __restrict__ Kb,
    const unsigned short* __restrict__ Vb, int kv0,
    unsigned short* kd, unsigned short* vd, int tid){
  #pragma unroll
  for (int qq=0; qq<4; qq++){
    int flat = qq*128 + tid;           // 0..511 : 64 rows x 8 chunks of 8 bf16
    int row = flat >> 3, ch = flat & 7;
    int sch = ch ^ (row & 7);          // pre-swizzled global source, linear LDS dest
    lds16(Kb + (size_t)(kv0+row)*DH + sch*8, kd + (size_t)flat*8);
    lds16(Vb + (size_t)row*SS + kv0 + sch*8, vd + (size_t)flat*8);
  }
}

__device__ __forceinline__ void attn_tile(const unsigned short* kc, const unsigned short* vc,
    unsigned short* pw, const bf16x8 aq[2][2], int qmin, int kv0,
    f32x4 o[2][4], float mrow[2][4], float lrow[2][4], int lr, int lg){
  // S = Q K^T (pre-scaled by 1/8 at projection)
  f32x4 sf[2][4];
  #pragma unroll
  for (int cb=0;cb<4;cb++){
    int krow = cb*16 + lr;
    bf16x8 bk0 = *reinterpret_cast<const bf16x8*>(kc + krow*64 + ((lg       ^ (krow&7))<<3));
    bf16x8 bk1 = *reinterpret_cast<const bf16x8*>(kc + krow*64 + (((4+lg)   ^ (krow&7))<<3));
    #pragma unroll
    for (int rb=0;rb<2;rb++){
      f32x4 t = (f32x4){0.f,0.f,0.f,0.f};
      t = mfma_bf16(aq[rb][0], bk0, t);
      t = mfma_bf16(aq[rb][1], bk1, t);
      sf[rb][cb] = t;
    }
  }
  // causal mask (only the diagonal tile needs it)
  if (kv0 + 64 > qmin){
    #pragma unroll
    for (int rb=0;rb<2;rb++)
      #pragma unroll
      for (int cb=0;cb<4;cb++)
        #pragma unroll
        for (int j=0;j<4;j++){
          int qrow = qmin + rb*16 + lg*4 + j;
          int kv   = kv0 + cb*16 + lr;
          if (kv > qrow) sf[rb][cb][j] = -1e30f;
        }
  }
  // online softmax (wave-parallel reduce within 16-lane groups)
  #pragma unroll
  for (int rb=0;rb<2;rb++){
    #pragma unroll
    for (int j=0;j<4;j++){
      float pm = fmaxf(fmaxf(sf[rb][0][j], sf[rb][1][j]), fmaxf(sf[rb][2][j], sf[rb][3][j]));
      pm = redmax16(pm);
      float mn = fmaxf(mrow[rb][j], pm);
      float sc = __expf(mrow[rb][j] - mn);
      mrow[rb][j] = mn;
      float rsum = 0.f;
      #pragma unroll
      for (int cb=0;cb<4;cb++){
        float p = __expf(sf[rb][cb][j] - mn);
        sf[rb][cb][j] = p;
        rsum += p;
      }
      rsum = redsum16(rsum);
      lrow[rb][j] = lrow[rb][j]*sc + rsum;
      #pragma unroll
      for (int db=0;db<4;db++) o[rb][db][j] *= sc;
    }
    // write P (bf16) to per-wave swizzled LDS
    #pragma unroll
    for (int cb=0;cb<4;cb++){
      int pcol = cb*16 + lr;
      #pragma unroll
      for (int j=0;j<4;j++){
        int prow = rb*16 + lg*4 + j;
        pw[prow*64 + (((pcol>>3) ^ (prow&7))<<3) + (pcol&7)] = f2bf(sf[rb][cb][j]);
      }
    }
  }
  // PV: O += P * V   (A = P from LDS, B = Vt rows, contiguous-K)
  bf16x8 pa[2][2];
  #pragma unroll
  for (int rb=0;rb<2;rb++){
    int prow = rb*16 + lr;
    #pragma unroll
    for (int kk=0;kk<2;kk++)
      pa[rb][kk] = *reinterpret_cast<const bf16x8*>(pw + prow*64 + (((kk*4+lg) ^ (prow&7))<<3));
  }
  #pragma unroll
  for (int db=0;db<4;db++){
    int vrow = db*16 + lr;
    bf16x8 bv0 = *reinterpret_cast<const bf16x8*>(vc + vrow*64 + ((lg     ^ (vrow&7))<<3));
    bf16x8 bv1 = *reinterpret_cast<const bf16x8*>(vc + vrow*64 + (((4+lg) ^ (vrow&7))<<3));
    #pragma unroll
    for (int rb=0;rb<2;rb++){
      o[rb][db] = mfma_bf16(pa[rb][0], bv0, o[rb][db]);
      o[rb][db] = mfma_bf16(pa[rb][1], bv1, o[rb][db]);
    }
  }
}

__device__ __forceinline__ void attn_epilogue(unsigned short* __restrict__ Zp, int b, int h,
    int qmin, f32x4 o[2][4], float lrow[2][4], int lr, int lg){
  #pragma unroll
  for (int rb=0;rb<2;rb++){
    float inv[4];
    #pragma unroll
    for (int j=0;j<4;j++) inv[j] = 1.f / lrow[rb][j];
    #pragma unroll
    for (int db=0;db<4;db++){
      #pragma unroll
      for (int j=0;j<4;j++){
        int s   = qmin + rb*16 + lg*4 + j;
        int col = h*DH + db*16 + lr;
        Zp[(size_t)(b*SS + s)*DM + col] = f2bf(o[rb][db][j] * inv[j]);
      }
    }
  }
}

__global__ __launch_bounds__(128, 2)
void k_attn(const unsigned short* __restrict__ Qp, const unsigned short* __restrict__ Kp,
            const unsigned short* __restrict__ Vp, unsigned short* __restrict__ Zp){
  __shared__ __align__(16) unsigned short kl[2][64*64];
  __shared__ __align__(16) unsigned short vl[2][64*64];
  __shared__ __align__(16) unsigned short pl[2*32*64];
  const int bh = blockIdx.y;
  const int pi = blockIdx.x;          // pair index 0..7
  const int qtA = pi, qtB = 15 - pi;  // 64-row q-tile indices
  const int nA = qtA + 1, nB = qtB + 1, nT = nA + nB;   // = 17 for every block
  const int tid = threadIdx.x;
  const int lane = tid & 63;
  const int w = tid >> 6;             // 2 waves
  const int lr = lane & 15;
  const int lg = lane >> 4;
  const unsigned short* Qb = Qp + (size_t)bh * (SS*DH);
  const unsigned short* Kb = Kp + (size_t)bh * (SS*DH);
  const unsigned short* Vb = Vp + (size_t)bh * (DH*SS);
  const int qminA = qtA*64 + w*32, qminB = qtB*64 + w*32;
  const int b = bh / NH, h = bh - b*NH;
  unsigned short* pw = pl + w*(32*64);

  // hoist Q fragments for both phases (pre-scaled by 1/8 at projection)
  bf16x8 aqA[2][2], aqB[2][2];
  #pragma unroll
  for (int rb=0;rb<2;rb++)
    #pragma unroll
    for (int kk=0;kk<2;kk++){
      aqA[rb][kk] = *reinterpret_cast<const bf16x8*>(Qb + (size_t)(qminA + rb*16 + lr)*DH + kk*32 + lg*8);
      aqB[rb][kk] = *reinterpret_cast<const bf16x8*>(Qb + (size_t)(qminB + rb*16 + lr)*DH + kk*32 + lg*8);
    }

  f32x4 o[2][4];
  float mrow[2][4], lrow[2][4];
  #pragma unroll
  for (int rb=0;rb<2;rb++){
    #pragma unroll
    for (int db=0;db<4;db++) o[rb][db] = (f32x4){0.f,0.f,0.f,0.f};
    #pragma unroll
    for (int j=0;j<4;j++){ mrow[rb][j] = -1e30f; lrow[rb][j] = 0.f; }
  }

  // prologue: stage global tile 0 into buffer 0
  attn_stage(Kb, Vb, 0, kl[0], vl[0], tid);
  __syncthreads();

  // phase A: global tiles s in [0, nA)  (kv0 = s*64)
  for (int s = 0; s < nA; ++s){
    int cur = s & 1;
    int nxt = s + 1;
    if (nxt < nT){
      int kv0n = (nxt < nA ? nxt : nxt - nA) * 64;
      attn_stage(Kb, Vb, kv0n, kl[cur^1], vl[cur^1], tid);
    }
    attn_tile(kl[cur], vl[cur], pw, aqA, qminA, s*64, o, mrow, lrow, lr, lg);
    __syncthreads();
  }
  attn_epilogue(Zp, b, h, qminA, o, lrow, lr, lg);
  #pragma unroll
  for (int rb=0;rb<2;rb++){
    #pragma unroll
    for (int db=0;db<4;db++) o[rb][db] = (f32x4){0.f,0.f,0.f,0.f};
    #pragma unroll
    for (int j=0;j<4;j++){ mrow[rb][j] = -1e30f; lrow[rb][j] = 0.f; }
  }

  // phase B: global tiles s in [nA, nT)  (kv0 = (s-nA)*64)
  for (int s = nA; s < nT; ++s){
    int cur = s & 1;
    int nxt = s + 1;
    if (nxt < nT){
      int kv0n = (nxt - nA) * 64;
      attn_stage(Kb, Vb, kv0n, kl[cur^1], vl[cur^1], tid);
    }
    attn_tile(kl[cur], vl[cur], pw, aqB, qminB, (s - nA)*64, o, mrow, lrow, lr, lg);
    __syncthreads();
  }
  attn_epilogue(Zp, b, h, qminB, o, lrow, lr, lg);
}

// ---------------- launch ----------------

extern "C" void kernel_launch(void* const* d_in, const int* in_sizes, int n_in,
                              void* d_out, int out_size, void* d_ws, size_t ws_size,
                              hipStream_t stream){
  const float* x  = (const float*)d_in[0];
  const float* wq = (const float*)d_in[1];
  const float* wk = (const float*)d_in[2];
  const float* wv = (const float*)d_in[3];
  const float* wo = (const float*)d_in[4];
  const float* bq = (const float*)d_in[5];
  const float* bk = (const float*)d_in[6];
  const float* bv = (const float*)d_in[7];
  const float* bo = (const float*)d_in[8];
  float* out = (float*)d_out;

  char* ws = (char*)d_ws;
  const size_t SZ_X  = (size_t)BS*DM*2;      // 12,582,912
  const size_t SZ_W  = (size_t)QKVN*DM*2;    //  3,538,944
  const size_t SZ_WO = (size_t)DM*DM*2;      //  1,179,648
  unsigned short* xbf   = (unsigned short*)(ws);
  unsigned short* wqkvt = (unsigned short*)(ws + SZ_X);
  unsigned short* wot   = (unsigned short*)(ws + SZ_X + SZ_W);
  unsigned short* Qw    = (unsigned short*)(ws + SZ_X + SZ_W + SZ_WO);
  unsigned short* Kw    = (unsigned short*)(ws + SZ_X + SZ_W + SZ_WO + SZ_X);
  unsigned short* Vw    = (unsigned short*)(ws + SZ_X + SZ_W + SZ_WO + 2*SZ_X);
  unsigned short* Zw    = xbf;               // x consumed by QKV GEMM before attn writes Z

  k_cvt_bf16<<<dim3(1024), dim3(256), 0, stream>>>(x, xbf, (BS*DM)/4);
  // W_Q/K/V: [12][768][64] -> [12][64][768]  (B^T layout rows c = qkv*768 + h*64 + d)
  k_transpose_bf16<<<dim3(1,12,12),  dim3(256), 0, stream>>>(wq, wqkvt,              DM, DH);
  k_transpose_bf16<<<dim3(1,12,12),  dim3(256), 0, stream>>>(wk, wqkvt +   DM*DM,    DM, DH);
  k_transpose_bf16<<<dim3(1,12,12),  dim3(256), 0, stream>>>(wv, wqkvt + 2*DM*DM,    DM, DH);
  // W_O: [768 hd][768 m] -> [768 m][768 hd]
  k_transpose_bf16<<<dim3(12,12,1),  dim3(256), 0, stream>>>(wo, wot, DM, DM);

  k_gemm_qkv<<<dim3(QKVN/128, BS/128), dim3(256), 0, stream>>>(xbf, wqkvt, bq, bk, bv, Qw, Kw, Vw);
  k_attn    <<<dim3(SS/64/2, BB*NH),   dim3(128), 0, stream>>>(Qw, Kw, Vw, Zw);
  k_gemm_out<<<dim3(DM/128, BS/128),   dim3(256), 0, stream>>>(Zw, wot, bo, out);
}